// Round 5
// baseline (44.672 us; speedup 1.0000x reference)
//
#include <hip/hip_runtime.h>
#include <math.h>

#define DV   256      // d_model
#define BB   64       // batch
#define LL   512      // seq len
#define DEG2 16       // 2 * n_degree
#define VV   8000     // vocab
#define CC   4        // n_category
#define LPW  4        // l's per wave
#define NW   4        // waves per block
#define LCB  (LPW*NW) // l's per block = 16
#define NLC  (LL/LCB) // 32 blocks along L
#define LN_EPS 1e-5f

typedef _Float16 half4 __attribute__((ext_vector_type(4)));
typedef float    f32x4 __attribute__((ext_vector_type(4)));

// ---------------- Kernel 1: LN the table once, emit fp16 rows ----------------
__global__ void __launch_bounds__(64) ln_rows_kernel(
    const float* __restrict__ emb, const float* __restrict__ gamma,
    const float* __restrict__ beta, half4* __restrict__ out)
{
    const int row = blockIdx.x;
    const int ln  = threadIdx.x;               // 0..63

    const f32x4 v = ((const f32x4*)(emb + row * DV))[ln];

    float s = v[0] + v[1] + v[2] + v[3];
    #pragma unroll
    for (int off = 32; off > 0; off >>= 1) s += __shfl_xor(s, off);
    const float mu = s * (1.0f / DV);

    f32x4 c;
    #pragma unroll
    for (int k = 0; k < 4; ++k) c[k] = v[k] - mu;

    float q = c[0]*c[0] + c[1]*c[1] + c[2]*c[2] + c[3]*c[3];
    #pragma unroll
    for (int off = 32; off > 0; off >>= 1) q += __shfl_xor(q, off);
    const float rs = rsqrtf(q * (1.0f / DV) + LN_EPS);

    const f32x4 g  = ((const f32x4*)gamma)[ln];
    const f32x4 bt = ((const f32x4*)beta)[ln];

    half4 h;
    #pragma unroll
    for (int k = 0; k < 4; ++k) h[k] = (_Float16)(c[k] * rs * g[k] + bt[k]);
    out[row * 64 + ln] = h;
}

// ---------------- Kernel 2: fused edge-gather + max-aggregate + blend + partial L-sum ----------------
// block = (b, lc); 4 waves; each wave owns 4 consecutive l's (= 64 edges, one per lane).
// Edge data is broadcast via __shfl with immediate lane -> no LDS round-trip, no mid-kernel barrier.
__global__ void __launch_bounds__(256) gnn_kernel(
    const int*   __restrict__ nb_x,
    const int*   __restrict__ w_edge,
    const float* __restrict__ we_table,
    const int*   __restrict__ x,
    const float* __restrict__ eta_table,
    const half4* __restrict__ norm_emb,   // [VV*64], 8B per lane-chunk
    float*       __restrict__ h_part)     // [BB][NLC][DV]
{
    const int b   = blockIdx.x;
    const int lc  = blockIdx.y;
    const int tid = threadIdx.x;
    const int w   = tid >> 6;
    const int ln  = tid & 63;

    const int l0   = lc * LCB + w * LPW;        // wave's first l
    const int base = b * LL + l0;               // wave-uniform

    // ---- phase 1: coalesced edge loads + random we gather (one edge per lane) ----
    // nt: streamed/random data must not evict the L2-resident norm_emb table.
    const int   nbv = __builtin_nontemporal_load(nb_x   + base * DEG2 + ln);
    const int   eiv = __builtin_nontemporal_load(w_edge + base * DEG2 + ln);
    const float wev = __builtin_nontemporal_load(we_table + eiv);   // random 4B from 256MB

    int xv = 0; float etv = 0.0f;
    if (ln < LPW) { xv = x[base + ln]; etv = eta_table[xv]; }

    // ---- phase 2: row gathers from L2-resident fp16 table, packed-fp16 max ----
    f32x4 acc = {0.0f, 0.0f, 0.0f, 0.0f};

    #pragma unroll
    for (int li = 0; li < LPW; ++li) {
        half4 m;
        m[0] = m[1] = m[2] = m[3] = (_Float16)(-65504.0f);   // -fp16_max

        #pragma unroll
        for (int j = 0; j < DEG2; ++j) {
            const int   lane = li * DEG2 + j;          // compile-time lane
            const int   idx  = __shfl(nbv, lane);      // wave-uniform
            const float wej  = __shfl(wev, lane);
            half4 wh;
            wh[0] = wh[1] = wh[2] = wh[3] = (_Float16)wej;
            const half4 e = norm_emb[idx * 64 + ln];
            m = __builtin_elementwise_max(m, wh * e);  // v_pk_mul_f16 + v_pk_max_f16
        }

        const int   sidx = __shfl(xv, li);
        const float eta  = __shfl(etv, li);
        const half4 se   = norm_emb[sidx * 64 + ln];
        const float om   = 1.0f - eta;

        #pragma unroll
        for (int k = 0; k < 4; ++k)
            acc[k] += om * (float)m[k] + eta * (float)se[k];
    }

    // ---- phase 3: reduce the 4 waves' partials, one write per block ----
    __shared__ float s_acc[NW][DV];
    ((f32x4*)s_acc[w])[ln] = acc;
    __syncthreads();
    if (w == 0) {
        f32x4 r0 = ((f32x4*)s_acc[0])[ln];
        f32x4 r1 = ((f32x4*)s_acc[1])[ln];
        f32x4 r2 = ((f32x4*)s_acc[2])[ln];
        f32x4 r3 = ((f32x4*)s_acc[3])[ln];
        f32x4 r;
        #pragma unroll
        for (int k = 0; k < 4; ++k) r[k] = r0[k] + r1[k] + r2[k] + r3[k];
        __builtin_nontemporal_store(r, (f32x4*)(h_part + (b * NLC + lc) * DV) + ln);
    }
}

// ---------------- Kernel 3: reduce partials over lc, then FC ----------------
__global__ void __launch_bounds__(256) fc_kernel(
    const float* __restrict__ h_part,
    const float* __restrict__ fc_w,
    const float* __restrict__ fc_b,
    float*       __restrict__ out)
{
    const int b  = blockIdx.x;
    const int d  = threadIdx.x;       // 0..255
    const int w  = d >> 6;
    const int ln = d & 63;

    float h = 0.0f;
    #pragma unroll 8
    for (int lc = 0; lc < NLC; ++lc)
        h += h_part[(b * NLC + lc) * DV + d];

    float p[CC];
    #pragma unroll
    for (int c = 0; c < CC; ++c) p[c] = h * fc_w[d * CC + c];

    #pragma unroll
    for (int c = 0; c < CC; ++c)
        #pragma unroll
        for (int off = 32; off > 0; off >>= 1) p[c] += __shfl_xor(p[c], off);

    __shared__ float s_red[4][CC];
    if (ln == 0) {
        #pragma unroll
        for (int c = 0; c < CC; ++c) s_red[w][c] = p[c];
    }
    __syncthreads();
    if (d < CC)
        out[b * CC + d] = s_red[0][d] + s_red[1][d] + s_red[2][d] + s_red[3][d] + fc_b[d];
}

extern "C" void kernel_launch(void* const* d_in, const int* in_sizes, int n_in,
                              void* d_out, int out_size, void* d_ws, size_t ws_size,
                              hipStream_t stream) {
    const int*   x        = (const int*)  d_in[0];
    const int*   nb_x     = (const int*)  d_in[1];
    const int*   w_edge   = (const int*)  d_in[2];
    const float* emb_w    = (const float*)d_in[3];
    const float* we_table = (const float*)d_in[4];
    const float* eta_tab  = (const float*)d_in[5];
    const float* ln_gamma = (const float*)d_in[6];
    const float* ln_beta  = (const float*)d_in[7];
    const float* fc_w     = (const float*)d_in[8];
    const float* fc_b     = (const float*)d_in[9];
    float* out = (float*)d_out;

    // workspace layout
    char* ws = (char*)d_ws;
    half4* norm_emb = (half4*)(ws);                 // 8000*256*2 = 4,096,000 B
    float* h_part   = (float*)(ws + 4096000);       // 64*32*256*4 = 2,097,152 B

    ln_rows_kernel<<<VV, 64, 0, stream>>>(emb_w, ln_gamma, ln_beta, norm_emb);

    dim3 grid2(BB, NLC);
    gnn_kernel<<<grid2, 256, 0, stream>>>(nb_x, w_edge, we_table, x, eta_tab,
                                          norm_emb, h_part);

    fc_kernel<<<BB, 256, 0, stream>>>(h_part, fc_w, fc_b, out);
}